// Round 11
// baseline (154.204 us; speedup 1.0000x reference)
//
#include <hip/hip_runtime.h>
#include <stdint.h>

typedef unsigned short u16;
typedef __bf16 bf16x8 __attribute__((ext_vector_type(8)));
typedef float f32x4 __attribute__((ext_vector_type(4)));

#define SEQ    1024
#define DMODEL 1024
#define NB     4
#define NH     16
#define DH     64
#define QBLK   128
#define KVB    64
#define LOG2E  1.4426950408889634f

// ---------- bf16 helpers ----------
__device__ __forceinline__ u16 f2bf(float f) {
  uint32_t u = __builtin_bit_cast(uint32_t, f);
  u += 0x7fffu + ((u >> 16) & 1u);   // round-to-nearest-even
  return (u16)(u >> 16);
}
__device__ __forceinline__ u16 f2bf_rz(float f) {   // truncate (p>=0; bias cancels in P/l)
  return (u16)(__builtin_bit_cast(uint32_t, f) >> 16);
}
__device__ __forceinline__ float bf2f(u16 h) {
  uint32_t u = ((uint32_t)h) << 16;
  return __builtin_bit_cast(float, u);
}

#define MFMA16(a, b, c) __builtin_amdgcn_mfma_f32_16x16x32_bf16((a), (b), (c), 0, 0, 0)

// ---------- async global->LDS (16B) ----------
__device__ __forceinline__ void gload_lds16(const u16* g, uintptr_t lds_addr) {
  __builtin_amdgcn_global_load_lds(
      (__attribute__((address_space(1))) void*)(uintptr_t)g,
      (__attribute__((address_space(3))) void*)lds_addr,
      16, 0, 0);
}

// ---------------- rope cos/sin table: tab[t*32+fi] = (cos, sin) ----------------
__global__ void rope_table_kernel(float2* __restrict__ tab) {
  int i = blockIdx.x * blockDim.x + threadIdx.x;   // SEQ*32
  int t = i >> 5, fi = i & 31;
  float inv = exp2f((float)fi * (-13.287712379549449f / 32.0f)); // 10000^(-fi/32)
  float ang = (float)t * inv;
  float sn, cs;
  sincosf(ang, &sn, &cs);
  tab[i] = make_float2(cs, sn);
}

// ---------------- cast f32 -> bf16 (hi only), 8 elems / thread ----------------
__global__ void cast_kernel(const float* __restrict__ src, u16* __restrict__ hi, int n8) {
  int i = blockIdx.x * blockDim.x + threadIdx.x;
  if (i >= n8) return;
  float4 v0 = *(const float4*)(src + (size_t)i * 8);
  float4 v1 = *(const float4*)(src + (size_t)i * 8 + 4);
  union { u16 u[8]; uint4 v; } H;
  H.u[0] = f2bf(v0.x); H.u[1] = f2bf(v0.y); H.u[2] = f2bf(v0.z); H.u[3] = f2bf(v0.w);
  H.u[4] = f2bf(v1.x); H.u[5] = f2bf(v1.y); H.u[6] = f2bf(v1.z); H.u[7] = f2bf(v1.w);
  *(uint4*)(hi + (size_t)i * 8) = H.v;
}

// ---------------- split f32 -> (hi, lo) bf16, 8 elems / thread ----------------
__global__ void split_kernel(const float* __restrict__ src, u16* __restrict__ hi,
                             u16* __restrict__ lo, int n8) {
  int i = blockIdx.x * blockDim.x + threadIdx.x;
  if (i >= n8) return;
  float f[8];
  float4 v0 = *(const float4*)(src + (size_t)i * 8);
  float4 v1 = *(const float4*)(src + (size_t)i * 8 + 4);
  f[0] = v0.x; f[1] = v0.y; f[2] = v0.z; f[3] = v0.w;
  f[4] = v1.x; f[5] = v1.y; f[6] = v1.z; f[7] = v1.w;
  union { u16 u[8]; uint4 v; } H, L;
#pragma unroll
  for (int e = 0; e < 8; ++e) {
    u16 h = f2bf(f[e]);
    H.u[e] = h;
    L.u[e] = f2bf(f[e] - bf2f(h));
  }
  *(uint4*)(hi + (size_t)i * 8) = H.v;
  *(uint4*)(lo + (size_t)i * 8) = L.v;
}

// ---------------- GEMM: C = A @ B^T, BK=64, terms over B only ----------------
// nt=1: C = Ah*Bh. nt=2: C = Ah*Bh + Ah*Bl (A staged once).
// 8-slot XOR swizzle: 0 bank conflicts (R9-measured).
// NOTE: no XCD block swizzle — with grid (8,32,z) the natural dispatch maps
// XCD = blockIdx.x, giving each XCD one hot 512KB B-panel (R10's chunked
// remap forced full-B per XCD -> L2 thrash, +30us. Reverted.)
// mode 0 (+rope): RoPE via shfl_xor pair exchange + table, then hi/lo store.
// mode 1: bf16 transposed out (Vt[col][row]).
struct GemmPtrs {
  const u16* Bh[3]; const u16* Bl[3];
  u16* C0[3]; u16* C1[3];
  int nt[3]; int mode[3]; int rope[3];
};

__global__ __launch_bounds__(256) void gemm_bt_kernel(
    const u16* __restrict__ Ah,
    GemmPtrs P, float* __restrict__ CF, const float2* __restrict__ ropetab,
    int M, int N, int K, int out_f32)
{
  __shared__ __align__(16) u16 sA [128 * 64];   // 16 KB
  __shared__ __align__(16) u16 sBh[128 * 64];   // 16 KB
  __shared__ __align__(16) u16 sBl[128 * 64];   // 16 KB
  const int t = threadIdx.x, lane = t & 63;
  const int wave = t >> 6;
  const int g = lane >> 4, cl = lane & 15;
  const int z = blockIdx.z;
  const u16* Bh = P.Bh[z];
  const u16* Bl = P.Bl[z];
  const int nt = P.nt[z];
  const int n0 = blockIdx.x * 128, m0 = blockIdx.y * 128;
  const int wr = wave >> 1, wc = wave & 1;

  // staging: 128x64 u16 tile = 1024 x 16B chunks, 4/thread; linear LDS dest,
  // source col pre-swizzled (rule #21), read-side applies same XOR involution
  int srow[4], scol[4], soff[4];
#pragma unroll
  for (int j = 0; j < 4; ++j) {
    int c = j * 256 + t;
    srow[j] = c >> 3;
    scol[j] = ((c & 7) ^ (srow[j] & 7)) * 8;
    soff[j] = c * 16;
  }

  f32x4 acc[4][4] = {};

  for (int k0 = 0; k0 < K; k0 += 64) {
#pragma unroll
    for (int j = 0; j < 4; ++j) {
      gload_lds16(Ah + (size_t)(m0 + srow[j]) * K + k0 + scol[j], (uintptr_t)sA + soff[j]);
      gload_lds16(Bh + (size_t)(n0 + srow[j]) * K + k0 + scol[j], (uintptr_t)sBh + soff[j]);
    }
    if (nt == 2) {
#pragma unroll
      for (int j = 0; j < 4; ++j)
        gload_lds16(Bl + (size_t)(n0 + srow[j]) * K + k0 + scol[j], (uintptr_t)sBl + soff[j]);
    }
    __syncthreads();   // drains vmcnt(0): staging landed

    bf16x8 af[4][2];
#pragma unroll
    for (int m = 0; m < 4; ++m) {
      int row = wr * 64 + m * 16 + cl;
#pragma unroll
      for (int kk = 0; kk < 2; ++kk)
        af[m][kk] = *(const bf16x8*)&sA[row * 64 + (((kk * 4 + g) ^ (row & 7)) * 8)];
    }
#pragma unroll
    for (int n = 0; n < 4; ++n) {
      int row = wc * 64 + n * 16 + cl;
      int o0 = row * 64 + ((g ^ (row & 7)) * 8);
      int o1 = row * 64 + (((4 + g) ^ (row & 7)) * 8);
      bf16x8 bh0 = *(const bf16x8*)&sBh[o0];
      bf16x8 bh1 = *(const bf16x8*)&sBh[o1];
#pragma unroll
      for (int m = 0; m < 4; ++m) {
        acc[m][n] = MFMA16(af[m][0], bh0, acc[m][n]);
        acc[m][n] = MFMA16(af[m][1], bh1, acc[m][n]);
      }
      if (nt == 2) {
        bf16x8 bl0 = *(const bf16x8*)&sBl[o0];
        bf16x8 bl1 = *(const bf16x8*)&sBl[o1];
#pragma unroll
        for (int m = 0; m < 4; ++m) {
          acc[m][n] = MFMA16(af[m][0], bl0, acc[m][n]);
          acc[m][n] = MFMA16(af[m][1], bl1, acc[m][n]);
        }
      }
    }
    __syncthreads();
  }

  // epilogue: C/D layout col=lane&15, row=(lane>>4)*4+reg  [m89]
  if (out_f32) {
#pragma unroll
    for (int m = 0; m < 4; ++m)
#pragma unroll
      for (int n = 0; n < 4; ++n)
#pragma unroll
        for (int r = 0; r < 4; ++r) {
          int row = m0 + wr * 64 + m * 16 + g * 4 + r;
          int col = n0 + wc * 64 + n * 16 + cl;
          CF[(size_t)row * N + col] = acc[m][n][r];
        }
  } else if (P.mode[z] == 1) {
    u16* VT = P.C0[z];
#pragma unroll
    for (int m = 0; m < 4; ++m)
#pragma unroll
      for (int n = 0; n < 4; ++n) {
        int row0 = m0 + wr * 64 + m * 16 + g * 4;
        int col = n0 + wc * 64 + n * 16 + cl;
        union { u16 u[4]; uint2 v; } pk;
#pragma unroll
        for (int r = 0; r < 4; ++r) pk.u[r] = f2bf(acc[m][n][r]);
        *(uint2*)&VT[(size_t)col * M + row0] = pk.v;
      }
  } else {
    u16* Ch = P.C0[z];
    u16* Cl = P.C1[z];
    const bool dorope = P.rope[z] != 0;   // wave-uniform
    const bool oddl = lane & 1;
#pragma unroll
    for (int m = 0; m < 4; ++m)
#pragma unroll
      for (int n = 0; n < 4; ++n)
#pragma unroll
        for (int r = 0; r < 4; ++r) {
          int row = m0 + wr * 64 + m * 16 + g * 4 + r;
          int col = n0 + wc * 64 + n * 16 + cl;
          float v = acc[m][n][r];
          if (dorope) {
            // pair (2p,2p+1) lives in lanes (cl, cl+1) at same row
            float2 cs = ropetab[(row & (SEQ - 1)) * 32 + ((col >> 1) & 31)];
            float pv = __shfl_xor(v, 1);
            v = oddl ? (pv * cs.y + v * cs.x)    // o' = e*sin + o*cos
                     : (v * cs.x - pv * cs.y);   // e' = e*cos - o*sin
          }
          u16 h = f2bf(v);
          Ch[(size_t)row * N + col] = h;
          Cl[(size_t)row * N + col] = f2bf(v - bf2f(h));
        }
  }
}

// ---------------- flash attention: LDS-shared K/V, 2-phase pipeline, no-max ----------------
// (R8/R9 structure, validated.) P store via truncation (bias cancels in P/l),
// LDS read offsets hoisted out of the kt loop.
__global__ __launch_bounds__(256, 2) void attn_kernel(
    const u16* __restrict__ Qh, const u16* __restrict__ Ql,
    const u16* __restrict__ Kh, const u16* __restrict__ Kl,
    const u16* __restrict__ Vt,
    u16* __restrict__ Oh)
{
  __shared__ __align__(16) u16 sKh[2][KVB * 64];   // [buf][key][d]  16KB
  __shared__ __align__(16) u16 sKl[2][KVB * 64];   // 16KB
  __shared__ __align__(16) u16 sVt[2][DH * KVB];   // [buf][d][key]  16KB
  __shared__ __align__(16) u16 sP[128 * 72];       // 18KB, wave-private rows

  const int t = threadIdx.x, lane = t & 63, wave = t >> 6;
  const int g = lane >> 4, cl = lane & 15;
  const int h = blockIdx.x & (NH - 1), b = blockIdx.x >> 4;
  const int y = blockIdx.y;
  const int qi = (y < 4) ? (7 - y) : (y - 4);  // paired work balance + heavy-first
  const int q0 = qi * QBLK;
  const size_t rowbase = (size_t)b * SEQ;
  const int colbase = h * DH;
  const int MT = NB * SEQ;

  const u16* Khb = Kh + rowbase * DMODEL + colbase;
  const u16* Klb = Kl + rowbase * DMODEL + colbase;
  const u16* Vtb = Vt + (size_t)(h * DH) * MT + b * SEQ;

  int srow[2], scol[2], soff[2];
#pragma unroll
  for (int j = 0; j < 2; ++j) {
    int c = j * 256 + t;
    srow[j] = c >> 3;
    scol[j] = ((c & 7) ^ (srow[j] & 7)) * 8;
    soff[j] = c * 16;
  }

  // loop-invariant LDS read offsets (kt loop is not unrolled)
  int koff0[4], koff1[4];
#pragma unroll
  for (int n = 0; n < 4; ++n) {
    int row = n * 16 + cl;
    koff0[n] = row * 64 + ((g ^ (row & 7)) * 8);
    koff1[n] = row * 64 + (((4 + g) ^ (row & 7)) * 8);
  }
  int paoff[2][2];
#pragma unroll
  for (int kk = 0; kk < 2; ++kk) {
    paoff[kk][0] = (wave * 32 + cl) * 72 + kk * 32 + g * 8;
    paoff[kk][1] = (wave * 32 + 16 + cl) * 72 + kk * 32 + g * 8;
  }

  // Q fragments (A-op: lane holds A[row=cl][k=g*8+e], second mfma k+32)
  bf16x8 qfh[2][2], qfl[2][2];
#pragma unroll
  for (int mf = 0; mf < 2; ++mf) {
    int qrow = q0 + wave * 32 + mf * 16 + cl;
    const u16* ph = Qh + (rowbase + qrow) * DMODEL + colbase + g * 8;
    const u16* pl = Ql + (rowbase + qrow) * DMODEL + colbase + g * 8;
    qfh[mf][0] = *(const bf16x8*)ph; qfh[mf][1] = *(const bf16x8*)(ph + 32);
    qfl[mf][0] = *(const bf16x8*)pl; qfl[mf][1] = *(const bf16x8*)(pl + 32);
  }

  bf16x8 ones;
#pragma unroll
  for (int e = 0; e < 8; ++e) ones[e] = (__bf16)1.0f;

  f32x4 o_acc[2][4] = {};
  f32x4 o_l[2] = {};

  const int last = 2 * qi + 1;
  const int wrow0 = q0 + wave * 32;
  const int prow0 = wave * 32;

  // prologue: stage tile 0 into buffer 0
#pragma unroll
  for (int j = 0; j < 2; ++j) {
    gload_lds16(Khb + (size_t)srow[j] * DMODEL + scol[j], (uintptr_t)&sKh[0][0] + soff[j]);
    gload_lds16(Klb + (size_t)srow[j] * DMODEL + scol[j], (uintptr_t)&sKl[0][0] + soff[j]);
    gload_lds16(Vtb + (size_t)srow[j] * MT + scol[j],     (uintptr_t)&sVt[0][0] + soff[j]);
  }
  __syncthreads();

  int cur = 0;
  for (int kt = 0; kt <= last; ++kt) {
    const int kv0 = kt * KVB;
    // issue next tile's staging FIRST (hidden under this tile's compute)
    if (kt < last) {
      const int nk = kv0 + KVB;
#pragma unroll
      for (int j = 0; j < 2; ++j) {
        gload_lds16(Khb + (size_t)(nk + srow[j]) * DMODEL + scol[j],
                    (uintptr_t)&sKh[cur ^ 1][0] + soff[j]);
        gload_lds16(Klb + (size_t)(nk + srow[j]) * DMODEL + scol[j],
                    (uintptr_t)&sKl[cur ^ 1][0] + soff[j]);
        gload_lds16(Vtb + (size_t)srow[j] * MT + nk + scol[j],
                    (uintptr_t)&sVt[cur ^ 1][0] + soff[j]);
      }
    }

    const bool skip = (wrow0 + 31) < kv0;   // wave fully masked (diag tiles)
    if (!skip) {
      const bool needmask = (kv0 + 63) > wrow0;

      // QK^T: 3-term split precision from LDS
      f32x4 s[2][4];
      __builtin_amdgcn_s_setprio(1);
#pragma unroll
      for (int n = 0; n < 4; ++n) {
        bf16x8 kh0 = *(const bf16x8*)&sKh[cur][koff0[n]];
        bf16x8 kh1 = *(const bf16x8*)&sKh[cur][koff1[n]];
        bf16x8 kl0 = *(const bf16x8*)&sKl[cur][koff0[n]];
        bf16x8 kl1 = *(const bf16x8*)&sKl[cur][koff1[n]];
#pragma unroll
        for (int mf = 0; mf < 2; ++mf) {
          f32x4 zz = {};
          zz = MFMA16(qfh[mf][0], kh0, zz);
          zz = MFMA16(qfh[mf][1], kh1, zz);
          zz = MFMA16(qfh[mf][0], kl0, zz);
          zz = MFMA16(qfh[mf][1], kl1, zz);
          zz = MFMA16(qfl[mf][0], kh0, zz);
          zz = MFMA16(qfl[mf][1], kh1, zz);
          s[mf][n] = zz;
        }
      }
      __builtin_amdgcn_s_setprio(0);

      // no-max softmax: p = exp2(s*log2e), zeroed past the diagonal
#pragma unroll
      for (int mf = 0; mf < 2; ++mf) {
#pragma unroll
        for (int r = 0; r < 4; ++r) {
          int qg = wrow0 + mf * 16 + g * 4 + r;
          int prow = prow0 + mf * 16 + g * 4 + r;
#pragma unroll
          for (int n = 0; n < 4; ++n) {
            float p = exp2f(s[mf][n][r] * LOG2E);
            if (needmask && (kv0 + n * 16 + cl > qg)) p = 0.0f;
            sP[prow * 72 + n * 16 + cl] = f2bf_rz(p);
          }
        }
      }

      // PV: O += P(32x64)*Vt ; l += P*1 (ones column)
      __builtin_amdgcn_s_setprio(1);
#pragma unroll
      for (int kk = 0; kk < 2; ++kk) {
        bf16x8 pa0 = *(const bf16x8*)&sP[paoff[kk][0]];
        bf16x8 pa1 = *(const bf16x8*)&sP[paoff[kk][1]];
#pragma unroll
        for (int n = 0; n < 4; ++n) {
          bf16x8 vf = *(const bf16x8*)&sVt[cur][(kk == 0) ? koff0[n] : koff1[n]];
          o_acc[0][n] = MFMA16(pa0, vf, o_acc[0][n]);
          o_acc[1][n] = MFMA16(pa1, vf, o_acc[1][n]);
        }
        o_l[0] = MFMA16(pa0, ones, o_l[0]);
        o_l[1] = MFMA16(pa1, ones, o_l[1]);
      }
      __builtin_amdgcn_s_setprio(0);
    }

    __syncthreads();   // drains vmcnt(0): prefetch landed; frees buf cur
    cur ^= 1;
  }

  // epilogue: normalize by l, store bf16 (hi only — Wo is 1-term)
#pragma unroll
  for (int mf = 0; mf < 2; ++mf)
#pragma unroll
    for (int n = 0; n < 4; ++n)
#pragma unroll
      for (int r = 0; r < 4; ++r) {
        float ov = o_acc[mf][n][r] / o_l[mf][r];
        int qrow = q0 + wave * 32 + mf * 16 + g * 4 + r;
        size_t idx = (rowbase + qrow) * DMODEL + colbase + n * 16 + cl;
        Oh[idx] = f2bf(ov);
      }
}

extern "C" void kernel_launch(void* const* d_in, const int* in_sizes, int n_in,
                              void* d_out, int out_size, void* d_ws, size_t ws_size,
                              hipStream_t stream) {
  const float* x  = (const float*)d_in[0];
  const float* Wq = (const float*)d_in[1];
  const float* Wk = (const float*)d_in[2];
  const float* Wv = (const float*)d_in[3];
  const float* Wo = (const float*)d_in[4];
  float* out = (float*)d_out;

  const int M = NB * SEQ;      // 4096
  const int D = DMODEL;        // 1024
  char* ws = (char*)d_ws;
  const size_t MB = 1u << 20;
  u16* xh  = (u16*)(ws + 0 * MB);    // 8 MB
  u16* qh  = (u16*)(ws + 8 * MB);
  u16* ql  = (u16*)(ws + 16 * MB);
  u16* kh  = (u16*)(ws + 24 * MB);
  u16* kl  = (u16*)(ws + 32 * MB);
  u16* vt  = (u16*)(ws + 40 * MB);   // V transposed: [1024 cols][4096 tokens]
  u16* oh  = (u16*)(ws + 48 * MB);
  u16* wqh = (u16*)(ws + 56 * MB);
  u16* wql = (u16*)(ws + 58 * MB);
  u16* wkh = (u16*)(ws + 60 * MB);
  u16* wkl = (u16*)(ws + 62 * MB);
  u16* wvh = (u16*)(ws + 64 * MB);
  u16* woh = (u16*)(ws + 66 * MB);
  float2* ropetab = (float2*)(ws + 68 * MB);   // 256 KB

  // rope table + casts (hi only: x, Wv, Wo) + splits (hi+lo: Wq, Wk)
  rope_table_kernel<<<SEQ * 32 / 256, 256, 0, stream>>>(ropetab);
  cast_kernel<<<(M * D / 8 + 255) / 256, 256, 0, stream>>>(x, xh, M * D / 8);
  split_kernel<<<(D * D / 8 + 255) / 256, 256, 0, stream>>>(Wq, wqh, wql, D * D / 8);
  split_kernel<<<(D * D / 8 + 255) / 256, 256, 0, stream>>>(Wk, wkh, wkl, D * D / 8);
  cast_kernel<<<(D * D / 8 + 255) / 256, 256, 0, stream>>>(Wv, wvh, D * D / 8);
  cast_kernel<<<(D * D / 8 + 255) / 256, 256, 0, stream>>>(Wo, woh, D * D / 8);

  // fused QKV projections: Q,K 2-term + fused RoPE, hi/lo out; V 1-term, Vt out
  {
    GemmPtrs P;
    P.Bh[0] = wqh; P.Bh[1] = wkh; P.Bh[2] = wvh;
    P.Bl[0] = wql; P.Bl[1] = wkl; P.Bl[2] = nullptr;
    P.C0[0] = qh;  P.C0[1] = kh;  P.C0[2] = vt;
    P.C1[0] = ql;  P.C1[1] = kl;  P.C1[2] = nullptr;
    P.nt[0] = 2;   P.nt[1] = 2;   P.nt[2] = 1;
    P.mode[0] = 0; P.mode[1] = 0; P.mode[2] = 1;
    P.rope[0] = 1; P.rope[1] = 1; P.rope[2] = 0;
    gemm_bt_kernel<<<dim3(D / 128, M / 128, 3), 256, 0, stream>>>(
        xh, P, nullptr, ropetab, M, D, D, 0);
  }

  // causal flash attention: 512 blocks of 4 waves, pair-balanced heavy-first
  attn_kernel<<<dim3(NH * NB, 8), 256, 0, stream>>>(qh, ql, kh, kl, vt, oh);

  // output projection, 1-term bf16, f32 out
  {
    GemmPtrs P;
    P.Bh[0] = woh; P.Bh[1] = woh; P.Bh[2] = woh;
    P.Bl[0] = nullptr; P.Bl[1] = nullptr; P.Bl[2] = nullptr;
    P.C0[0] = nullptr; P.C0[1] = nullptr; P.C0[2] = nullptr;
    P.C1[0] = nullptr; P.C1[1] = nullptr; P.C1[2] = nullptr;
    P.nt[0] = 1;   P.nt[1] = 1;   P.nt[2] = 1;
    P.mode[0] = 0; P.mode[1] = 0; P.mode[2] = 0;
    P.rope[0] = 0; P.rope[1] = 0; P.rope[2] = 0;
    gemm_bt_kernel<<<dim3(D / 128, M / 128, 1), 256, 0, stream>>>(
        oh, P, out, ropetab, M, D, D, 1);
  }
}

// Round 12
// 140.204 us; speedup vs baseline: 1.0999x; 1.0999x over previous
//
#include <hip/hip_runtime.h>
#include <stdint.h>

typedef unsigned short u16;
typedef __bf16 bf16x8 __attribute__((ext_vector_type(8)));
typedef float f32x4 __attribute__((ext_vector_type(4)));

#define SEQ    1024
#define DMODEL 1024
#define NB     4
#define NH     16
#define DH     64
#define QBLK   128
#define KVB    64
#define LOG2E  1.4426950408889634f

// ---------- bf16 helpers ----------
__device__ __forceinline__ u16 f2bf(float f) {
  uint32_t u = __builtin_bit_cast(uint32_t, f);
  u += 0x7fffu + ((u >> 16) & 1u);   // round-to-nearest-even
  return (u16)(u >> 16);
}
__device__ __forceinline__ u16 f2bf_rz(float f) {   // truncate (p>=0; bias cancels in P/l)
  return (u16)(__builtin_bit_cast(uint32_t, f) >> 16);
}
__device__ __forceinline__ float bf2f(u16 h) {
  uint32_t u = ((uint32_t)h) << 16;
  return __builtin_bit_cast(float, u);
}

#define MFMA16(a, b, c) __builtin_amdgcn_mfma_f32_16x16x32_bf16((a), (b), (c), 0, 0, 0)

// ---------- async global->LDS (16B) ----------
__device__ __forceinline__ void gload_lds16(const u16* g, uintptr_t lds_addr) {
  __builtin_amdgcn_global_load_lds(
      (__attribute__((address_space(1))) void*)(uintptr_t)g,
      (__attribute__((address_space(3))) void*)lds_addr,
      16, 0, 0);
}

// ---------------- cast f32 -> bf16 (hi only), 8 elems / thread ----------------
__global__ void cast_kernel(const float* __restrict__ src, u16* __restrict__ hi, int n8) {
  int i = blockIdx.x * blockDim.x + threadIdx.x;
  if (i >= n8) return;
  float4 v0 = *(const float4*)(src + (size_t)i * 8);
  float4 v1 = *(const float4*)(src + (size_t)i * 8 + 4);
  union { u16 u[8]; uint4 v; } H;
  H.u[0] = f2bf(v0.x); H.u[1] = f2bf(v0.y); H.u[2] = f2bf(v0.z); H.u[3] = f2bf(v0.w);
  H.u[4] = f2bf(v1.x); H.u[5] = f2bf(v1.y); H.u[6] = f2bf(v1.z); H.u[7] = f2bf(v1.w);
  *(uint4*)(hi + (size_t)i * 8) = H.v;
}

// ---------------- split f32 -> (hi, lo) bf16, 8 elems / thread ----------------
__global__ void split_kernel(const float* __restrict__ src, u16* __restrict__ hi,
                             u16* __restrict__ lo, int n8) {
  int i = blockIdx.x * blockDim.x + threadIdx.x;
  if (i >= n8) return;
  float f[8];
  float4 v0 = *(const float4*)(src + (size_t)i * 8);
  float4 v1 = *(const float4*)(src + (size_t)i * 8 + 4);
  f[0] = v0.x; f[1] = v0.y; f[2] = v0.z; f[3] = v0.w;
  f[4] = v1.x; f[5] = v1.y; f[6] = v1.z; f[7] = v1.w;
  union { u16 u[8]; uint4 v; } H, L;
#pragma unroll
  for (int e = 0; e < 8; ++e) {
    u16 h = f2bf(f[e]);
    H.u[e] = h;
    L.u[e] = f2bf(f[e] - bf2f(h));
  }
  *(uint4*)(hi + (size_t)i * 8) = H.v;
  *(uint4*)(lo + (size_t)i * 8) = L.v;
}

// ---------------- RoPE on Q,K hi/lo pairs (in place; R9-validated ~10us) ----------------
__global__ void rope_kernel(u16* __restrict__ Qh, u16* __restrict__ Ql,
                            u16* __restrict__ Kh, u16* __restrict__ Kl) {
  const int nP = (NB * SEQ) * (DMODEL / 2);
  int idx = blockIdx.x * blockDim.x + threadIdx.x;
  u16 *bh, *bl; int p;
  if (idx < nP) { bh = Qh; bl = Ql; p = idx; }
  else          { bh = Kh; bl = Kl; p = idx - nP; }
  int row = p >> 9;           // 512 pairs per row
  int pi  = p & 511;
  int t   = row & (SEQ - 1);
  int fi  = pi & 31;
  float inv = exp2f((float)fi * (-13.287712379549449f / 32.0f)); // 10000^(-fi/32)
  float ang = (float)t * inv;
  float sn, cs;
  sincosf(ang, &sn, &cs);
  size_t off = (size_t)row * DMODEL + pi * 2;
  uint32_t vh = *(uint32_t*)(bh + off);
  uint32_t vl = *(uint32_t*)(bl + off);
  float e = bf2f((u16)(vh & 0xffffu)) + bf2f((u16)(vl & 0xffffu));
  float o = bf2f((u16)(vh >> 16))     + bf2f((u16)(vl >> 16));
  float re = e * cs - o * sn;
  float ro = e * sn + o * cs;
  u16 reh = f2bf(re), roh = f2bf(ro);
  u16 rel = f2bf(re - bf2f(reh)), rol = f2bf(ro - bf2f(roh));
  *(uint32_t*)(bh + off) = (uint32_t)reh | ((uint32_t)roh << 16);
  *(uint32_t*)(bl + off) = (uint32_t)rel | ((uint32_t)rol << 16);
}

// ---------------- f32 add: out = p0 + p1, 8 elems / thread ----------------
__global__ void add_kernel(const float* __restrict__ p0, const float* __restrict__ p1,
                           float* __restrict__ out, int n8) {
  int i = blockIdx.x * blockDim.x + threadIdx.x;
  if (i >= n8) return;
  float4 a0 = *(const float4*)(p0 + (size_t)i * 8);
  float4 a1 = *(const float4*)(p0 + (size_t)i * 8 + 4);
  float4 b0 = *(const float4*)(p1 + (size_t)i * 8);
  float4 b1 = *(const float4*)(p1 + (size_t)i * 8 + 4);
  float4 c0 = make_float4(a0.x + b0.x, a0.y + b0.y, a0.z + b0.z, a0.w + b0.w);
  float4 c1 = make_float4(a1.x + b1.x, a1.y + b1.y, a1.z + b1.z, a1.w + b1.w);
  *(float4*)(out + (size_t)i * 8) = c0;
  *(float4*)(out + (size_t)i * 8 + 4) = c1;
}

// ---------------- GEMM: C = A @ B^T, BK=64, terms over B only ----------------
// nt=1: C = Ah*Bh. nt=2: C = Ah*Bh + Ah*Bl (A staged once).
// 8-slot XOR swizzle: 0 bank conflicts (R9-measured). No XCD/rope tricks
// (R10/R11: rope-fused epilogue cost ~33us; XCD chunk remap thrashed L2).
// out_f32: grid.z splits K; z writes its partial to CF + z*M*N (split-K:
// 1 block/CU -> 2 blocks/CU, halves the latency-exposed 2-phase loop).
// mode 1: bf16 transposed out (Vt[col][row]).
struct GemmPtrs {
  const u16* Bh[3]; const u16* Bl[3];
  u16* C0[3]; u16* C1[3];
  int nt[3]; int mode[3];
};

__global__ __launch_bounds__(256) void gemm_bt_kernel(
    const u16* __restrict__ Ah,
    GemmPtrs P, float* __restrict__ CF,
    int M, int N, int K, int out_f32)
{
  __shared__ __align__(16) u16 sA [128 * 64];   // 16 KB
  __shared__ __align__(16) u16 sBh[128 * 64];   // 16 KB
  __shared__ __align__(16) u16 sBl[128 * 64];   // 16 KB
  const int t = threadIdx.x, lane = t & 63;
  const int wave = t >> 6;
  const int g = lane >> 4, cl = lane & 15;
  const int z = blockIdx.z;
  const u16* Bh = P.Bh[z];
  const u16* Bl = P.Bl[z];
  const int nt = P.nt[z];
  const int n0 = blockIdx.x * 128, m0 = blockIdx.y * 128;
  const int wr = wave >> 1, wc = wave & 1;

  // split-K for f32-output launches: z owns K-range, writes its own partial
  int kb = 0, ke = K;
  if (out_f32) {
    int kc = K / gridDim.z;
    kb = z * kc; ke = kb + kc;
    CF += (size_t)z * M * N;
  }

  // staging: 128x64 u16 tile = 1024 x 16B chunks, 4/thread; linear LDS dest,
  // source col pre-swizzled (rule #21), read-side applies same XOR involution
  int srow[4], scol[4], soff[4];
#pragma unroll
  for (int j = 0; j < 4; ++j) {
    int c = j * 256 + t;
    srow[j] = c >> 3;
    scol[j] = ((c & 7) ^ (srow[j] & 7)) * 8;
    soff[j] = c * 16;
  }

  f32x4 acc[4][4] = {};

  for (int k0 = kb; k0 < ke; k0 += 64) {
#pragma unroll
    for (int j = 0; j < 4; ++j) {
      gload_lds16(Ah + (size_t)(m0 + srow[j]) * K + k0 + scol[j], (uintptr_t)sA + soff[j]);
      gload_lds16(Bh + (size_t)(n0 + srow[j]) * K + k0 + scol[j], (uintptr_t)sBh + soff[j]);
    }
    if (nt == 2) {
#pragma unroll
      for (int j = 0; j < 4; ++j)
        gload_lds16(Bl + (size_t)(n0 + srow[j]) * K + k0 + scol[j], (uintptr_t)sBl + soff[j]);
    }
    __syncthreads();   // drains vmcnt(0): staging landed

    bf16x8 af[4][2];
#pragma unroll
    for (int m = 0; m < 4; ++m) {
      int row = wr * 64 + m * 16 + cl;
#pragma unroll
      for (int kk = 0; kk < 2; ++kk)
        af[m][kk] = *(const bf16x8*)&sA[row * 64 + (((kk * 4 + g) ^ (row & 7)) * 8)];
    }
#pragma unroll
    for (int n = 0; n < 4; ++n) {
      int row = wc * 64 + n * 16 + cl;
      int o0 = row * 64 + ((g ^ (row & 7)) * 8);
      int o1 = row * 64 + (((4 + g) ^ (row & 7)) * 8);
      bf16x8 bh0 = *(const bf16x8*)&sBh[o0];
      bf16x8 bh1 = *(const bf16x8*)&sBh[o1];
#pragma unroll
      for (int m = 0; m < 4; ++m) {
        acc[m][n] = MFMA16(af[m][0], bh0, acc[m][n]);
        acc[m][n] = MFMA16(af[m][1], bh1, acc[m][n]);
      }
      if (nt == 2) {
        bf16x8 bl0 = *(const bf16x8*)&sBl[o0];
        bf16x8 bl1 = *(const bf16x8*)&sBl[o1];
#pragma unroll
        for (int m = 0; m < 4; ++m) {
          acc[m][n] = MFMA16(af[m][0], bl0, acc[m][n]);
          acc[m][n] = MFMA16(af[m][1], bl1, acc[m][n]);
        }
      }
    }
    __syncthreads();
  }

  // epilogue: C/D layout col=lane&15, row=(lane>>4)*4+reg  [m89]
  if (out_f32) {
#pragma unroll
    for (int m = 0; m < 4; ++m)
#pragma unroll
      for (int n = 0; n < 4; ++n)
#pragma unroll
        for (int r = 0; r < 4; ++r) {
          int row = m0 + wr * 64 + m * 16 + g * 4 + r;
          int col = n0 + wc * 64 + n * 16 + cl;
          CF[(size_t)row * N + col] = acc[m][n][r];
        }
  } else if (P.mode[z] == 1) {
    u16* VT = P.C0[z];
#pragma unroll
    for (int m = 0; m < 4; ++m)
#pragma unroll
      for (int n = 0; n < 4; ++n) {
        int row0 = m0 + wr * 64 + m * 16 + g * 4;
        int col = n0 + wc * 64 + n * 16 + cl;
        union { u16 u[4]; uint2 v; } pk;
#pragma unroll
        for (int r = 0; r < 4; ++r) pk.u[r] = f2bf(acc[m][n][r]);
        *(uint2*)&VT[(size_t)col * M + row0] = pk.v;
      }
  } else {
    u16* Ch = P.C0[z];
    u16* Cl = P.C1[z];
#pragma unroll
    for (int m = 0; m < 4; ++m)
#pragma unroll
      for (int n = 0; n < 4; ++n)
#pragma unroll
        for (int r = 0; r < 4; ++r) {
          int row = m0 + wr * 64 + m * 16 + g * 4 + r;
          int col = n0 + wc * 64 + n * 16 + cl;
          float v = acc[m][n][r];
          u16 h = f2bf(v);
          Ch[(size_t)row * N + col] = h;
          Cl[(size_t)row * N + col] = f2bf(v - bf2f(h));
        }
  }
}

// ---------------- flash attention: LDS-shared K/V, 2-phase pipeline, no-max ----------------
// (R8/R9 structure, validated.) P store via truncation (bias cancels in P/l),
// LDS read offsets hoisted out of the kt loop.
__global__ __launch_bounds__(256, 2) void attn_kernel(
    const u16* __restrict__ Qh, const u16* __restrict__ Ql,
    const u16* __restrict__ Kh, const u16* __restrict__ Kl,
    const u16* __restrict__ Vt,
    u16* __restrict__ Oh)
{
  __shared__ __align__(16) u16 sKh[2][KVB * 64];   // [buf][key][d]  16KB
  __shared__ __align__(16) u16 sKl[2][KVB * 64];   // 16KB
  __shared__ __align__(16) u16 sVt[2][DH * KVB];   // [buf][d][key]  16KB
  __shared__ __align__(16) u16 sP[128 * 72];       // 18KB, wave-private rows

  const int t = threadIdx.x, lane = t & 63, wave = t >> 6;
  const int g = lane >> 4, cl = lane & 15;
  const int h = blockIdx.x & (NH - 1), b = blockIdx.x >> 4;
  const int y = blockIdx.y;
  const int qi = (y < 4) ? (7 - y) : (y - 4);  // paired work balance + heavy-first
  const int q0 = qi * QBLK;
  const size_t rowbase = (size_t)b * SEQ;
  const int colbase = h * DH;
  const int MT = NB * SEQ;

  const u16* Khb = Kh + rowbase * DMODEL + colbase;
  const u16* Klb = Kl + rowbase * DMODEL + colbase;
  const u16* Vtb = Vt + (size_t)(h * DH) * MT + b * SEQ;

  int srow[2], scol[2], soff[2];
#pragma unroll
  for (int j = 0; j < 2; ++j) {
    int c = j * 256 + t;
    srow[j] = c >> 3;
    scol[j] = ((c & 7) ^ (srow[j] & 7)) * 8;
    soff[j] = c * 16;
  }

  // loop-invariant LDS read offsets (kt loop is not unrolled)
  int koff0[4], koff1[4];
#pragma unroll
  for (int n = 0; n < 4; ++n) {
    int row = n * 16 + cl;
    koff0[n] = row * 64 + ((g ^ (row & 7)) * 8);
    koff1[n] = row * 64 + (((4 + g) ^ (row & 7)) * 8);
  }
  int paoff[2][2];
#pragma unroll
  for (int kk = 0; kk < 2; ++kk) {
    paoff[kk][0] = (wave * 32 + cl) * 72 + kk * 32 + g * 8;
    paoff[kk][1] = (wave * 32 + 16 + cl) * 72 + kk * 32 + g * 8;
  }

  // Q fragments (A-op: lane holds A[row=cl][k=g*8+e], second mfma k+32)
  bf16x8 qfh[2][2], qfl[2][2];
#pragma unroll
  for (int mf = 0; mf < 2; ++mf) {
    int qrow = q0 + wave * 32 + mf * 16 + cl;
    const u16* ph = Qh + (rowbase + qrow) * DMODEL + colbase + g * 8;
    const u16* pl = Ql + (rowbase + qrow) * DMODEL + colbase + g * 8;
    qfh[mf][0] = *(const bf16x8*)ph; qfh[mf][1] = *(const bf16x8*)(ph + 32);
    qfl[mf][0] = *(const bf16x8*)pl; qfl[mf][1] = *(const bf16x8*)(pl + 32);
  }

  bf16x8 ones;
#pragma unroll
  for (int e = 0; e < 8; ++e) ones[e] = (__bf16)1.0f;

  f32x4 o_acc[2][4] = {};
  f32x4 o_l[2] = {};

  const int last = 2 * qi + 1;
  const int wrow0 = q0 + wave * 32;
  const int prow0 = wave * 32;

  // prologue: stage tile 0 into buffer 0
#pragma unroll
  for (int j = 0; j < 2; ++j) {
    gload_lds16(Khb + (size_t)srow[j] * DMODEL + scol[j], (uintptr_t)&sKh[0][0] + soff[j]);
    gload_lds16(Klb + (size_t)srow[j] * DMODEL + scol[j], (uintptr_t)&sKl[0][0] + soff[j]);
    gload_lds16(Vtb + (size_t)srow[j] * MT + scol[j],     (uintptr_t)&sVt[0][0] + soff[j]);
  }
  __syncthreads();

  int cur = 0;
  for (int kt = 0; kt <= last; ++kt) {
    const int kv0 = kt * KVB;
    // issue next tile's staging FIRST (hidden under this tile's compute)
    if (kt < last) {
      const int nk = kv0 + KVB;
#pragma unroll
      for (int j = 0; j < 2; ++j) {
        gload_lds16(Khb + (size_t)(nk + srow[j]) * DMODEL + scol[j],
                    (uintptr_t)&sKh[cur ^ 1][0] + soff[j]);
        gload_lds16(Klb + (size_t)(nk + srow[j]) * DMODEL + scol[j],
                    (uintptr_t)&sKl[cur ^ 1][0] + soff[j]);
        gload_lds16(Vtb + (size_t)srow[j] * MT + nk + scol[j],
                    (uintptr_t)&sVt[cur ^ 1][0] + soff[j]);
      }
    }

    const bool skip = (wrow0 + 31) < kv0;   // wave fully masked (diag tiles)
    if (!skip) {
      const bool needmask = (kv0 + 63) > wrow0;

      // QK^T: 3-term split precision from LDS
      f32x4 s[2][4];
      __builtin_amdgcn_s_setprio(1);
#pragma unroll
      for (int n = 0; n < 4; ++n) {
        bf16x8 kh0 = *(const bf16x8*)&sKh[cur][koff0[n]];
        bf16x8 kh1 = *(const bf16x8*)&sKh[cur][koff1[n]];
        bf16x8 kl0 = *(const bf16x8*)&sKl[cur][koff0[n]];
        bf16x8 kl1 = *(const bf16x8*)&sKl[cur][koff1[n]];
#pragma unroll
        for (int mf = 0; mf < 2; ++mf) {
          f32x4 zz = {};
          zz = MFMA16(qfh[mf][0], kh0, zz);
          zz = MFMA16(qfh[mf][1], kh1, zz);
          zz = MFMA16(qfh[mf][0], kl0, zz);
          zz = MFMA16(qfh[mf][1], kl1, zz);
          zz = MFMA16(qfl[mf][0], kh0, zz);
          zz = MFMA16(qfl[mf][1], kh1, zz);
          s[mf][n] = zz;
        }
      }
      __builtin_amdgcn_s_setprio(0);

      // no-max softmax: p = exp2(s*log2e), zeroed past the diagonal
#pragma unroll
      for (int mf = 0; mf < 2; ++mf) {
#pragma unroll
        for (int r = 0; r < 4; ++r) {
          int qg = wrow0 + mf * 16 + g * 4 + r;
          int prow = prow0 + mf * 16 + g * 4 + r;
#pragma unroll
          for (int n = 0; n < 4; ++n) {
            float p = exp2f(s[mf][n][r] * LOG2E);
            if (needmask && (kv0 + n * 16 + cl > qg)) p = 0.0f;
            sP[prow * 72 + n * 16 + cl] = f2bf_rz(p);
          }
        }
      }

      // PV: O += P(32x64)*Vt ; l += P*1 (ones column)
      __builtin_amdgcn_s_setprio(1);
#pragma unroll
      for (int kk = 0; kk < 2; ++kk) {
        bf16x8 pa0 = *(const bf16x8*)&sP[paoff[kk][0]];
        bf16x8 pa1 = *(const bf16x8*)&sP[paoff[kk][1]];
#pragma unroll
        for (int n = 0; n < 4; ++n) {
          bf16x8 vf = *(const bf16x8*)&sVt[cur][(kk == 0) ? koff0[n] : koff1[n]];
          o_acc[0][n] = MFMA16(pa0, vf, o_acc[0][n]);
          o_acc[1][n] = MFMA16(pa1, vf, o_acc[1][n]);
        }
        o_l[0] = MFMA16(pa0, ones, o_l[0]);
        o_l[1] = MFMA16(pa1, ones, o_l[1]);
      }
      __builtin_amdgcn_s_setprio(0);
    }

    __syncthreads();   // drains vmcnt(0): prefetch landed; frees buf cur
    cur ^= 1;
  }

  // epilogue: normalize by l, store bf16 (hi only — Wo is 1-term)
#pragma unroll
  for (int mf = 0; mf < 2; ++mf)
#pragma unroll
    for (int n = 0; n < 4; ++n)
#pragma unroll
      for (int r = 0; r < 4; ++r) {
        float ov = o_acc[mf][n][r] / o_l[mf][r];
        int qrow = q0 + wave * 32 + mf * 16 + g * 4 + r;
        size_t idx = (rowbase + qrow) * DMODEL + colbase + n * 16 + cl;
        Oh[idx] = f2bf(ov);
      }
}

extern "C" void kernel_launch(void* const* d_in, const int* in_sizes, int n_in,
                              void* d_out, int out_size, void* d_ws, size_t ws_size,
                              hipStream_t stream) {
  const float* x  = (const float*)d_in[0];
  const float* Wq = (const float*)d_in[1];
  const float* Wk = (const float*)d_in[2];
  const float* Wv = (const float*)d_in[3];
  const float* Wo = (const float*)d_in[4];
  float* out = (float*)d_out;

  const int M = NB * SEQ;      // 4096
  const int D = DMODEL;        // 1024
  char* ws = (char*)d_ws;
  const size_t MB = 1u << 20;
  u16* xh  = (u16*)(ws + 0 * MB);    // 8 MB
  u16* qh  = (u16*)(ws + 8 * MB);
  u16* ql  = (u16*)(ws + 16 * MB);
  u16* kh  = (u16*)(ws + 24 * MB);
  u16* kl  = (u16*)(ws + 32 * MB);
  u16* vt  = (u16*)(ws + 40 * MB);   // V transposed: [1024 cols][4096 tokens]
  u16* oh  = (u16*)(ws + 48 * MB);
  u16* wqh = (u16*)(ws + 56 * MB);
  u16* wql = (u16*)(ws + 58 * MB);
  u16* wkh = (u16*)(ws + 60 * MB);
  u16* wkl = (u16*)(ws + 62 * MB);
  u16* wvh = (u16*)(ws + 64 * MB);
  u16* woh = (u16*)(ws + 66 * MB);
  // split-K partials for Wo reuse q/k buffers (dead after attn): 2 x 16 MB f32
  float* wo_part = (float*)(ws + 8 * MB);    // spans qh..kl (8..40 MB)

  // casts (hi only: x, Wv, Wo) and splits (hi+lo: Wq, Wk)
  cast_kernel<<<(M * D / 8 + 255) / 256, 256, 0, stream>>>(x, xh, M * D / 8);
  split_kernel<<<(D * D / 8 + 255) / 256, 256, 0, stream>>>(Wq, wqh, wql, D * D / 8);
  split_kernel<<<(D * D / 8 + 255) / 256, 256, 0, stream>>>(Wk, wkh, wkl, D * D / 8);
  cast_kernel<<<(D * D / 8 + 255) / 256, 256, 0, stream>>>(Wv, wvh, D * D / 8);
  cast_kernel<<<(D * D / 8 + 255) / 256, 256, 0, stream>>>(Wo, woh, D * D / 8);

  // fused QKV projections: Q,K 2-term (xh*(Wh+Wl)), hi/lo out; V 1-term, Vt out
  {
    GemmPtrs P;
    P.Bh[0] = wqh; P.Bh[1] = wkh; P.Bh[2] = wvh;
    P.Bl[0] = wql; P.Bl[1] = wkl; P.Bl[2] = nullptr;
    P.C0[0] = qh;  P.C0[1] = kh;  P.C0[2] = vt;
    P.C1[0] = ql;  P.C1[1] = kl;  P.C1[2] = nullptr;
    P.nt[0] = 2;   P.nt[1] = 2;   P.nt[2] = 1;
    P.mode[0] = 0; P.mode[1] = 0; P.mode[2] = 1;
    gemm_bt_kernel<<<dim3(D / 128, M / 128, 3), 256, 0, stream>>>(
        xh, P, nullptr, M, D, D, 0);
  }

  // RoPE on Q,K (hi/lo, in place)
  rope_kernel<<<(2 * M * (D / 2) + 255) / 256, 256, 0, stream>>>(qh, ql, kh, kl);

  // causal flash attention: 512 blocks of 4 waves, pair-balanced heavy-first
  attn_kernel<<<dim3(NH * NB, 8), 256, 0, stream>>>(qh, ql, kh, kl, vt, oh);

  // output projection, 1-term bf16, split-K=2 into f32 partials, then add
  {
    GemmPtrs P;
    P.Bh[0] = woh; P.Bh[1] = woh; P.Bh[2] = woh;
    P.Bl[0] = nullptr; P.Bl[1] = nullptr; P.Bl[2] = nullptr;
    P.C0[0] = nullptr; P.C0[1] = nullptr; P.C0[2] = nullptr;
    P.C1[0] = nullptr; P.C1[1] = nullptr; P.C1[2] = nullptr;
    P.nt[0] = 1;   P.nt[1] = 1;   P.nt[2] = 1;
    P.mode[0] = 0; P.mode[1] = 0; P.mode[2] = 0;
    gemm_bt_kernel<<<dim3(D / 128, M / 128, 2), 256, 0, stream>>>(
        oh, P, wo_part, M, D, D, 1);
    add_kernel<<<(M * D / 8 + 255) / 256, 256, 0, stream>>>(
        wo_part, wo_part + (size_t)M * D, out, M * D / 8);
  }
}

// Round 13
// 121.615 us; speedup vs baseline: 1.2680x; 1.1529x over previous
//
#include <hip/hip_runtime.h>
#include <stdint.h>

typedef unsigned short u16;
typedef short s16x8 __attribute__((ext_vector_type(8)));
typedef __bf16 bf16x8 __attribute__((ext_vector_type(8)));
typedef _Float16 f16x8 __attribute__((ext_vector_type(8)));
typedef float f32x4 __attribute__((ext_vector_type(4)));

#define SEQ    1024
#define DMODEL 1024
#define NB     4
#define NH     16
#define DH     64
#define QBLK   128
#define KVB    64
#define LOG2E  1.4426950408889634f

// ---------- scalar conversion helpers ----------
__device__ __forceinline__ u16 f2bf(float f) {
  uint32_t u = __builtin_bit_cast(uint32_t, f);
  u += 0x7fffu + ((u >> 16) & 1u);   // round-to-nearest-even
  return (u16)(u >> 16);
}
__device__ __forceinline__ u16 f2bf_rz(float f) {   // truncate (p>=0; bias cancels in P/l)
  return (u16)(__builtin_bit_cast(uint32_t, f) >> 16);
}
__device__ __forceinline__ float bf2f(u16 h) {
  uint32_t u = ((uint32_t)h) << 16;
  return __builtin_bit_cast(float, u);
}
__device__ __forceinline__ u16 f2h(float f) {       // f32 -> fp16 RNE
  return __builtin_bit_cast(u16, (_Float16)f);
}
__device__ __forceinline__ float h2f(u16 u) {
  return (float)__builtin_bit_cast(_Float16, u);
}

#define MFMA16(a, b, c)  __builtin_amdgcn_mfma_f32_16x16x32_bf16((a), (b), (c), 0, 0, 0)
#define MFMA16H(a, b, c) __builtin_amdgcn_mfma_f32_16x16x32_f16((a), (b), (c), 0, 0, 0)

template<bool F16>
__device__ __forceinline__ f32x4 MF(s16x8 a, s16x8 b, f32x4 c) {
  if constexpr (F16)
    return MFMA16H(__builtin_bit_cast(f16x8, a), __builtin_bit_cast(f16x8, b), c);
  else
    return MFMA16(__builtin_bit_cast(bf16x8, a), __builtin_bit_cast(bf16x8, b), c);
}

// ---------- async global->LDS (16B) ----------
__device__ __forceinline__ void gload_lds16(const u16* g, uintptr_t lds_addr) {
  __builtin_amdgcn_global_load_lds(
      (__attribute__((address_space(1))) void*)(uintptr_t)g,
      (__attribute__((address_space(3))) void*)lds_addr,
      16, 0, 0);
}

// ---------------- cast f32 -> bf16, 8 elems / thread ----------------
__global__ void cast_bf_kernel(const float* __restrict__ src, u16* __restrict__ dst, int n8) {
  int i = blockIdx.x * blockDim.x + threadIdx.x;
  if (i >= n8) return;
  float4 v0 = *(const float4*)(src + (size_t)i * 8);
  float4 v1 = *(const float4*)(src + (size_t)i * 8 + 4);
  union { u16 u[8]; uint4 v; } H;
  H.u[0] = f2bf(v0.x); H.u[1] = f2bf(v0.y); H.u[2] = f2bf(v0.z); H.u[3] = f2bf(v0.w);
  H.u[4] = f2bf(v1.x); H.u[5] = f2bf(v1.y); H.u[6] = f2bf(v1.z); H.u[7] = f2bf(v1.w);
  *(uint4*)(dst + (size_t)i * 8) = H.v;
}

// ---------------- cast f32 -> fp16, 8 elems / thread ----------------
__global__ void cast_h_kernel(const float* __restrict__ src, u16* __restrict__ dst, int n8) {
  int i = blockIdx.x * blockDim.x + threadIdx.x;
  if (i >= n8) return;
  float4 v0 = *(const float4*)(src + (size_t)i * 8);
  float4 v1 = *(const float4*)(src + (size_t)i * 8 + 4);
  union { u16 u[8]; uint4 v; } H;
  H.u[0] = f2h(v0.x); H.u[1] = f2h(v0.y); H.u[2] = f2h(v0.z); H.u[3] = f2h(v0.w);
  H.u[4] = f2h(v1.x); H.u[5] = f2h(v1.y); H.u[6] = f2h(v1.z); H.u[7] = f2h(v1.w);
  *(uint4*)(dst + (size_t)i * 8) = H.v;
}

// ---------------- RoPE on fp16 Q,K (in place) ----------------
__global__ void rope_kernel(u16* __restrict__ Q, u16* __restrict__ K) {
  const int nP = (NB * SEQ) * (DMODEL / 2);
  int idx = blockIdx.x * blockDim.x + threadIdx.x;
  u16* buf; int p;
  if (idx < nP) { buf = Q; p = idx; }
  else          { buf = K; p = idx - nP; }
  int row = p >> 9;           // 512 pairs per row
  int pi  = p & 511;
  int t   = row & (SEQ - 1);
  int fi  = pi & 31;
  float inv = exp2f((float)fi * (-13.287712379549449f / 32.0f)); // 10000^(-fi/32)
  float ang = (float)t * inv;
  float sn, cs;
  sincosf(ang, &sn, &cs);
  size_t off = (size_t)row * DMODEL + pi * 2;
  uint32_t v = *(uint32_t*)(buf + off);
  float e = h2f((u16)(v & 0xffffu));
  float o = h2f((u16)(v >> 16));
  float re = e * cs - o * sn;
  float ro = e * sn + o * cs;
  *(uint32_t*)(buf + off) = (uint32_t)f2h(re) | ((uint32_t)f2h(ro) << 16);
}

// ---------------- f32 add: out = p0 + p1, 8 elems / thread ----------------
__global__ void add_kernel(const float* __restrict__ p0, const float* __restrict__ p1,
                           float* __restrict__ out, int n8) {
  int i = blockIdx.x * blockDim.x + threadIdx.x;
  if (i >= n8) return;
  float4 a0 = *(const float4*)(p0 + (size_t)i * 8);
  float4 a1 = *(const float4*)(p0 + (size_t)i * 8 + 4);
  float4 b0 = *(const float4*)(p1 + (size_t)i * 8);
  float4 b1 = *(const float4*)(p1 + (size_t)i * 8 + 4);
  float4 c0 = make_float4(a0.x + b0.x, a0.y + b0.y, a0.z + b0.z, a0.w + b0.w);
  float4 c1 = make_float4(a1.x + b1.x, a1.y + b1.y, a1.z + b1.z, a1.w + b1.w);
  *(float4*)(out + (size_t)i * 8) = c0;
  *(float4*)(out + (size_t)i * 8 + 4) = c1;
}

// ---------------- GEMM: C = A @ B^T, BK=64, 1-term, dtype-templated ----------------
// F16=true: fp16 MFMA, mode-0 stores fp16. F16=false: bf16 MFMA.
// 8-slot XOR swizzle: 0 bank conflicts (R9-measured). No XCD remap, no fused
// rope (R10/R11 lessons). out_f32: grid.z splits K, z writes partial CF+z*M*N.
// mode 1: bf16 transposed out (Vt[col][row], feeds bf16 PV MFMA).
struct GemmPtrs {
  const u16* B[3]; u16* C0[3]; int mode[3];
};

template<bool F16>
__global__ __launch_bounds__(256) void gemm_bt_kernel(
    const u16* __restrict__ A,
    GemmPtrs P, float* __restrict__ CF,
    int M, int N, int K, int out_f32)
{
  __shared__ __align__(16) u16 sA[128 * 64];   // 16 KB
  __shared__ __align__(16) u16 sB[128 * 64];   // 16 KB
  const int t = threadIdx.x, lane = t & 63;
  const int wave = t >> 6;
  const int g = lane >> 4, cl = lane & 15;
  const int z = blockIdx.z;
  const u16* B = P.B[z];
  const int n0 = blockIdx.x * 128, m0 = blockIdx.y * 128;
  const int wr = wave >> 1, wc = wave & 1;

  int kb = 0, ke = K;
  if (out_f32) {                 // split-K partials
    int kc = K / gridDim.z;
    kb = z * kc; ke = kb + kc;
    CF += (size_t)z * M * N;
  }

  int srow[4], scol[4], soff[4];
#pragma unroll
  for (int j = 0; j < 4; ++j) {
    int c = j * 256 + t;
    srow[j] = c >> 3;
    scol[j] = ((c & 7) ^ (srow[j] & 7)) * 8;
    soff[j] = c * 16;
  }

  f32x4 acc[4][4] = {};

  for (int k0 = kb; k0 < ke; k0 += 64) {
#pragma unroll
    for (int j = 0; j < 4; ++j) {
      gload_lds16(A + (size_t)(m0 + srow[j]) * K + k0 + scol[j], (uintptr_t)sA + soff[j]);
      gload_lds16(B + (size_t)(n0 + srow[j]) * K + k0 + scol[j], (uintptr_t)sB + soff[j]);
    }
    __syncthreads();   // drains vmcnt(0): staging landed

    s16x8 af[4][2];
#pragma unroll
    for (int m = 0; m < 4; ++m) {
      int row = wr * 64 + m * 16 + cl;
#pragma unroll
      for (int kk = 0; kk < 2; ++kk)
        af[m][kk] = *(const s16x8*)&sA[row * 64 + (((kk * 4 + g) ^ (row & 7)) * 8)];
    }
#pragma unroll
    for (int n = 0; n < 4; ++n) {
      int row = wc * 64 + n * 16 + cl;
      s16x8 b0 = *(const s16x8*)&sB[row * 64 + ((g ^ (row & 7)) * 8)];
      s16x8 b1 = *(const s16x8*)&sB[row * 64 + (((4 + g) ^ (row & 7)) * 8)];
#pragma unroll
      for (int m = 0; m < 4; ++m) {
        acc[m][n] = MF<F16>(af[m][0], b0, acc[m][n]);
        acc[m][n] = MF<F16>(af[m][1], b1, acc[m][n]);
      }
    }
    __syncthreads();
  }

  // epilogue: C/D layout col=lane&15, row=(lane>>4)*4+reg  [m89]
  if (out_f32) {
#pragma unroll
    for (int m = 0; m < 4; ++m)
#pragma unroll
      for (int n = 0; n < 4; ++n)
#pragma unroll
        for (int r = 0; r < 4; ++r) {
          int row = m0 + wr * 64 + m * 16 + g * 4 + r;
          int col = n0 + wc * 64 + n * 16 + cl;
          CF[(size_t)row * N + col] = acc[m][n][r];
        }
  } else if (P.mode[z] == 1) {
    u16* VT = P.C0[z];
#pragma unroll
    for (int m = 0; m < 4; ++m)
#pragma unroll
      for (int n = 0; n < 4; ++n) {
        int row0 = m0 + wr * 64 + m * 16 + g * 4;
        int col = n0 + wc * 64 + n * 16 + cl;
        union { u16 u[4]; uint2 v; } pk;
#pragma unroll
        for (int r = 0; r < 4; ++r) pk.u[r] = f2bf(acc[m][n][r]);
        *(uint2*)&VT[(size_t)col * M + row0] = pk.v;
      }
  } else {
    u16* C = P.C0[z];
#pragma unroll
    for (int m = 0; m < 4; ++m)
#pragma unroll
      for (int n = 0; n < 4; ++n)
#pragma unroll
        for (int r = 0; r < 4; ++r) {
          int row = m0 + wr * 64 + m * 16 + g * 4 + r;
          int col = n0 + wc * 64 + n * 16 + cl;
          float v = acc[m][n][r];
          C[(size_t)row * N + col] = F16 ? f2h(v) : f2bf(v);
        }
  }
}

// ---------------- flash attention: fp16 QK^T, bf16 PV, no-max, 2-phase ----------------
// Q,K fp16 (1-term, 8x finer mantissa than bf16 -> QK chain error ~6x lower
// than the old 2-term bf16 split). P stays bf16 (exp(s) up to e^50 would
// overflow fp16); V bf16. LDS 50 KB -> 3 blocks/CU (was 2 at 66 KB).
__global__ __launch_bounds__(256, 2) void attn_kernel(
    const u16* __restrict__ Q, const u16* __restrict__ K,
    const u16* __restrict__ Vt,
    u16* __restrict__ Oh)
{
  __shared__ __align__(16) u16 sK [2][KVB * 64];   // fp16 [buf][key][d]  16KB
  __shared__ __align__(16) u16 sVt[2][DH * KVB];   // bf16 [buf][d][key]  16KB
  __shared__ __align__(16) u16 sP[128 * 72];       // bf16, 18KB, wave-private rows

  const int t = threadIdx.x, lane = t & 63, wave = t >> 6;
  const int g = lane >> 4, cl = lane & 15;
  const int h = blockIdx.x & (NH - 1), b = blockIdx.x >> 4;
  const int y = blockIdx.y;
  const int qi = (y < 4) ? (7 - y) : (y - 4);  // paired work balance + heavy-first
  const int q0 = qi * QBLK;
  const size_t rowbase = (size_t)b * SEQ;
  const int colbase = h * DH;
  const int MT = NB * SEQ;

  const u16* Kb  = K + rowbase * DMODEL + colbase;
  const u16* Vtb = Vt + (size_t)(h * DH) * MT + b * SEQ;

  int srow[2], scol[2], soff[2];
#pragma unroll
  for (int j = 0; j < 2; ++j) {
    int c = j * 256 + t;
    srow[j] = c >> 3;
    scol[j] = ((c & 7) ^ (srow[j] & 7)) * 8;
    soff[j] = c * 16;
  }

  // loop-invariant LDS read offsets
  int koff0[4], koff1[4];
#pragma unroll
  for (int n = 0; n < 4; ++n) {
    int row = n * 16 + cl;
    koff0[n] = row * 64 + ((g ^ (row & 7)) * 8);
    koff1[n] = row * 64 + (((4 + g) ^ (row & 7)) * 8);
  }
  int paoff[2][2];
#pragma unroll
  for (int kk = 0; kk < 2; ++kk) {
    paoff[kk][0] = (wave * 32 + cl) * 72 + kk * 32 + g * 8;
    paoff[kk][1] = (wave * 32 + 16 + cl) * 72 + kk * 32 + g * 8;
  }

  // Q fragments fp16 (A-op: lane holds A[row=cl][k=g*8+e], second mfma k+32)
  f16x8 qf[2][2];
#pragma unroll
  for (int mf = 0; mf < 2; ++mf) {
    int qrow = q0 + wave * 32 + mf * 16 + cl;
    const u16* pq = Q + (rowbase + qrow) * DMODEL + colbase + g * 8;
    qf[mf][0] = __builtin_bit_cast(f16x8, *(const s16x8*)pq);
    qf[mf][1] = __builtin_bit_cast(f16x8, *(const s16x8*)(pq + 32));
  }

  bf16x8 ones;
#pragma unroll
  for (int e = 0; e < 8; ++e) ones[e] = (__bf16)1.0f;

  f32x4 o_acc[2][4] = {};
  f32x4 o_l[2] = {};

  const int last = 2 * qi + 1;
  const int wrow0 = q0 + wave * 32;
  const int prow0 = wave * 32;

  // prologue: stage tile 0 into buffer 0
#pragma unroll
  for (int j = 0; j < 2; ++j) {
    gload_lds16(Kb + (size_t)srow[j] * DMODEL + scol[j],  (uintptr_t)&sK[0][0] + soff[j]);
    gload_lds16(Vtb + (size_t)srow[j] * MT + scol[j],     (uintptr_t)&sVt[0][0] + soff[j]);
  }
  __syncthreads();

  int cur = 0;
  for (int kt = 0; kt <= last; ++kt) {
    const int kv0 = kt * KVB;
    // issue next tile's staging FIRST (hidden under this tile's compute)
    if (kt < last) {
      const int nk = kv0 + KVB;
#pragma unroll
      for (int j = 0; j < 2; ++j) {
        gload_lds16(Kb + (size_t)(nk + srow[j]) * DMODEL + scol[j],
                    (uintptr_t)&sK[cur ^ 1][0] + soff[j]);
        gload_lds16(Vtb + (size_t)srow[j] * MT + nk + scol[j],
                    (uintptr_t)&sVt[cur ^ 1][0] + soff[j]);
      }
    }

    const bool skip = (wrow0 + 31) < kv0;   // wave fully masked (diag tiles)
    if (!skip) {
      const bool needmask = (kv0 + 63) > wrow0;

      // QK^T: fp16 single-term
      f32x4 s[2][4];
      __builtin_amdgcn_s_setprio(1);
#pragma unroll
      for (int n = 0; n < 4; ++n) {
        f16x8 k0 = __builtin_bit_cast(f16x8, *(const s16x8*)&sK[cur][koff0[n]]);
        f16x8 k1 = __builtin_bit_cast(f16x8, *(const s16x8*)&sK[cur][koff1[n]]);
#pragma unroll
        for (int mf = 0; mf < 2; ++mf) {
          f32x4 zz = {};
          zz = MFMA16H(qf[mf][0], k0, zz);
          zz = MFMA16H(qf[mf][1], k1, zz);
          s[mf][n] = zz;
        }
      }
      __builtin_amdgcn_s_setprio(0);

      // no-max softmax: p = exp2(s*log2e), zeroed past the diagonal
#pragma unroll
      for (int mf = 0; mf < 2; ++mf) {
#pragma unroll
        for (int r = 0; r < 4; ++r) {
          int qg = wrow0 + mf * 16 + g * 4 + r;
          int prow = prow0 + mf * 16 + g * 4 + r;
#pragma unroll
          for (int n = 0; n < 4; ++n) {
            float p = exp2f(s[mf][n][r] * LOG2E);
            if (needmask && (kv0 + n * 16 + cl > qg)) p = 0.0f;
            sP[prow * 72 + n * 16 + cl] = f2bf_rz(p);
          }
        }
      }

      // PV: O += P(32x64)*Vt ; l += P*1 (bf16 MFMA)
      __builtin_amdgcn_s_setprio(1);
#pragma unroll
      for (int kk = 0; kk < 2; ++kk) {
        bf16x8 pa0 = *(const bf16x8*)&sP[paoff[kk][0]];
        bf16x8 pa1 = *(const bf16x8*)&sP[paoff[kk][1]];
#pragma unroll
        for (int n = 0; n < 4; ++n) {
          bf16x8 vf = *(const bf16x8*)&sVt[cur][(kk == 0) ? koff0[n] : koff1[n]];
          o_acc[0][n] = MFMA16(pa0, vf, o_acc[0][n]);
          o_acc[1][n] = MFMA16(pa1, vf, o_acc[1][n]);
        }
        o_l[0] = MFMA16(pa0, ones, o_l[0]);
        o_l[1] = MFMA16(pa1, ones, o_l[1]);
      }
      __builtin_amdgcn_s_setprio(0);
    }

    __syncthreads();   // drains vmcnt(0): prefetch landed; frees buf cur
    cur ^= 1;
  }

  // epilogue: normalize by l, store bf16 (feeds bf16 Wo GEMM)
#pragma unroll
  for (int mf = 0; mf < 2; ++mf)
#pragma unroll
    for (int n = 0; n < 4; ++n)
#pragma unroll
      for (int r = 0; r < 4; ++r) {
        float ov = o_acc[mf][n][r] / o_l[mf][r];
        int qrow = q0 + wave * 32 + mf * 16 + g * 4 + r;
        size_t idx = (rowbase + qrow) * DMODEL + colbase + n * 16 + cl;
        Oh[idx] = f2bf(ov);
      }
}

extern "C" void kernel_launch(void* const* d_in, const int* in_sizes, int n_in,
                              void* d_out, int out_size, void* d_ws, size_t ws_size,
                              hipStream_t stream) {
  const float* x  = (const float*)d_in[0];
  const float* Wq = (const float*)d_in[1];
  const float* Wk = (const float*)d_in[2];
  const float* Wv = (const float*)d_in[3];
  const float* Wo = (const float*)d_in[4];
  float* out = (float*)d_out;

  const int M = NB * SEQ;      // 4096
  const int D = DMODEL;        // 1024
  char* ws = (char*)d_ws;
  const size_t MB = 1u << 20;
  u16* xh16 = (u16*)(ws + 0 * MB);    // 8 MB fp16
  u16* qh16 = (u16*)(ws + 8 * MB);    // 8 MB fp16
  u16* kh16 = (u16*)(ws + 16 * MB);   // 8 MB fp16
  u16* vt   = (u16*)(ws + 24 * MB);   // 8 MB bf16, transposed [1024][4096]
  u16* oh   = (u16*)(ws + 40 * MB);   // 8 MB bf16
  u16* wq16 = (u16*)(ws + 48 * MB);   // 2 MB each
  u16* wk16 = (u16*)(ws + 50 * MB);
  u16* wv16 = (u16*)(ws + 52 * MB);
  u16* wob  = (u16*)(ws + 54 * MB);
  // split-K partials reuse qh16/kh16/vt (dead after attn): 2 x 16 MB f32
  float* wo_part = (float*)(ws + 8 * MB);

  // casts: x, Wq, Wk, Wv -> fp16 ; Wo -> bf16
  cast_h_kernel<<<(M * D / 8 + 255) / 256, 256, 0, stream>>>(x, xh16, M * D / 8);
  cast_h_kernel<<<(D * D / 8 + 255) / 256, 256, 0, stream>>>(Wq, wq16, D * D / 8);
  cast_h_kernel<<<(D * D / 8 + 255) / 256, 256, 0, stream>>>(Wk, wk16, D * D / 8);
  cast_h_kernel<<<(D * D / 8 + 255) / 256, 256, 0, stream>>>(Wv, wv16, D * D / 8);
  cast_bf_kernel<<<(D * D / 8 + 255) / 256, 256, 0, stream>>>(Wo, wob, D * D / 8);

  // fused QKV projections, all fp16 1-term: Q,K fp16 out; V bf16 transposed out
  {
    GemmPtrs P;
    P.B[0] = wq16; P.B[1] = wk16; P.B[2] = wv16;
    P.C0[0] = qh16; P.C0[1] = kh16; P.C0[2] = vt;
    P.mode[0] = 0; P.mode[1] = 0; P.mode[2] = 1;
    gemm_bt_kernel<true><<<dim3(D / 128, M / 128, 3), 256, 0, stream>>>(
        xh16, P, nullptr, M, D, D, 0);
  }

  // RoPE on fp16 Q,K (in place)
  rope_kernel<<<(2 * M * (D / 2) + 255) / 256, 256, 0, stream>>>(qh16, kh16);

  // causal flash attention: 512 blocks of 4 waves, pair-balanced heavy-first
  attn_kernel<<<dim3(NH * NB, 8), 256, 0, stream>>>(qh16, kh16, vt, oh);

  // output projection, 1-term bf16, split-K=2 into f32 partials, then add
  {
    GemmPtrs P;
    P.B[0] = wob; P.B[1] = wob; P.B[2] = wob;
    P.C0[0] = nullptr; P.C0[1] = nullptr; P.C0[2] = nullptr;
    P.mode[0] = 0; P.mode[1] = 0; P.mode[2] = 0;
    gemm_bt_kernel<false><<<dim3(D / 128, M / 128, 2), 256, 0, stream>>>(
        oh, P, wo_part, M, D, D, 1);
    add_kernel<<<(M * D / 8 + 255) / 256, 256, 0, stream>>>(
        wo_part, wo_part + (size_t)M * D, out, M * D / 8);
  }
}

// Round 14
// 104.737 us; speedup vs baseline: 1.4723x; 1.1611x over previous
//
#include <hip/hip_runtime.h>
#include <stdint.h>

typedef unsigned short u16;
typedef short s16x8 __attribute__((ext_vector_type(8)));
typedef __bf16 bf16x8 __attribute__((ext_vector_type(8)));
typedef _Float16 f16x8 __attribute__((ext_vector_type(8)));
typedef float f32x4 __attribute__((ext_vector_type(4)));

#define SEQ    1024
#define DMODEL 1024
#define NB     4
#define NH     16
#define DH     64
#define QBLK   128
#define KVB    64
#define LOG2E  1.4426950408889634f

// ---------- scalar conversion helpers ----------
__device__ __forceinline__ u16 f2bf(float f) {
  uint32_t u = __builtin_bit_cast(uint32_t, f);
  u += 0x7fffu + ((u >> 16) & 1u);   // round-to-nearest-even
  return (u16)(u >> 16);
}
__device__ __forceinline__ u16 f2bf_rz(float f) {   // truncate (p>=0; bias cancels in P/l)
  return (u16)(__builtin_bit_cast(uint32_t, f) >> 16);
}
__device__ __forceinline__ float bf2f(u16 h) {
  uint32_t u = ((uint32_t)h) << 16;
  return __builtin_bit_cast(float, u);
}
__device__ __forceinline__ u16 f2h(float f) {       // f32 -> fp16 RNE
  return __builtin_bit_cast(u16, (_Float16)f);
}
__device__ __forceinline__ float h2f(u16 u) {
  return (float)__builtin_bit_cast(_Float16, u);
}

#define MFMA16(a, b, c)  __builtin_amdgcn_mfma_f32_16x16x32_bf16((a), (b), (c), 0, 0, 0)
#define MFMA16H(a, b, c) __builtin_amdgcn_mfma_f32_16x16x32_f16((a), (b), (c), 0, 0, 0)

template<bool F16>
__device__ __forceinline__ f32x4 MF(s16x8 a, s16x8 b, f32x4 c) {
  if constexpr (F16)
    return MFMA16H(__builtin_bit_cast(f16x8, a), __builtin_bit_cast(f16x8, b), c);
  else
    return MFMA16(__builtin_bit_cast(bf16x8, a), __builtin_bit_cast(bf16x8, b), c);
}

// ---------- async global->LDS (16B) ----------
__device__ __forceinline__ void gload_lds16(const u16* g, uintptr_t lds_addr) {
  __builtin_amdgcn_global_load_lds(
      (__attribute__((address_space(1))) void*)(uintptr_t)g,
      (__attribute__((address_space(3))) void*)lds_addr,
      16, 0, 0);
}

// ---------------- fused cast: x,Wq,Wk,Wv -> fp16 ; Wo -> bf16 (one launch) ----------------
__global__ void cast_all_kernel(
    const float* __restrict__ x, const float* __restrict__ wq,
    const float* __restrict__ wk, const float* __restrict__ wv,
    const float* __restrict__ wo,
    u16* __restrict__ xd, u16* __restrict__ wqd, u16* __restrict__ wkd,
    u16* __restrict__ wvd, u16* __restrict__ wod)
{
  const int NX = (NB * SEQ * DMODEL) / 8;   // 524288 chunks
  const int NW = (DMODEL * DMODEL) / 8;     // 131072 chunks
  int c = blockIdx.x * blockDim.x + threadIdx.x;
  const float* src; u16* dst; bool tobf = false;
  if (c < NX)                { src = x;  dst = xd; }
  else if ((c -= NX) < NW)   { src = wq; dst = wqd; }
  else if ((c -= NW) < NW)   { src = wk; dst = wkd; }
  else if ((c -= NW) < NW)   { src = wv; dst = wvd; }
  else if ((c -= NW) < NW)   { src = wo; dst = wod; tobf = true; }
  else return;
  float f[8];
  float4 v0 = *(const float4*)(src + (size_t)c * 8);
  float4 v1 = *(const float4*)(src + (size_t)c * 8 + 4);
  f[0] = v0.x; f[1] = v0.y; f[2] = v0.z; f[3] = v0.w;
  f[4] = v1.x; f[5] = v1.y; f[6] = v1.z; f[7] = v1.w;
  union { u16 u[8]; uint4 v; } H;
#pragma unroll
  for (int e = 0; e < 8; ++e) H.u[e] = tobf ? f2bf(f[e]) : f2h(f[e]);
  *(uint4*)(dst + (size_t)c * 8) = H.v;
}

// ---------------- RoPE on fp16 Q,K (in place) ----------------
__global__ void rope_kernel(u16* __restrict__ Q, u16* __restrict__ K) {
  const int nP = (NB * SEQ) * (DMODEL / 2);
  int idx = blockIdx.x * blockDim.x + threadIdx.x;
  u16* buf; int p;
  if (idx < nP) { buf = Q; p = idx; }
  else          { buf = K; p = idx - nP; }
  int row = p >> 9;           // 512 pairs per row
  int pi  = p & 511;
  int t   = row & (SEQ - 1);
  int fi  = pi & 31;
  float inv = exp2f((float)fi * (-13.287712379549449f / 32.0f)); // 10000^(-fi/32)
  float ang = (float)t * inv;
  float sn, cs;
  sincosf(ang, &sn, &cs);
  size_t off = (size_t)row * DMODEL + pi * 2;
  uint32_t v = *(uint32_t*)(buf + off);
  float e = h2f((u16)(v & 0xffffu));
  float o = h2f((u16)(v >> 16));
  float re = e * cs - o * sn;
  float ro = e * sn + o * cs;
  *(uint32_t*)(buf + off) = (uint32_t)f2h(re) | ((uint32_t)f2h(ro) << 16);
}

// ---------------- GEMM: C = A @ B^T, 128xBN tile, BK=64, dtype-templated ----------------
// F16=true: fp16 MFMA, mode-0 stores fp16. F16=false: bf16 MFMA.
// BN=128: QKV (4 waves 2x2, acc[4][4]).  BN=64: Wo direct-f32 (512 blocks =
// 2/CU, replaces split-K + add: no 80 MB partial traffic, one less kernel).
// 8-slot XOR swizzle: 0 bank conflicts (R9-measured). No XCD remap, no fused
// rope (R10/R11 lessons). mode 1: bf16 transposed out (Vt[col][row]).
struct GemmPtrs {
  const u16* B[3]; u16* C0[3]; int mode[3];
};

template<bool F16, int BN>
__global__ __launch_bounds__(256) void gemm_bt_kernel(
    const u16* __restrict__ A,
    GemmPtrs P, float* __restrict__ CF,
    int M, int N, int K, int out_f32)
{
  constexpr int NF = BN / 32;                   // n-frags per wave
  constexpr int BCH = BN / 32;                  // B staging chunks per thread
  __shared__ __align__(16) u16 sA[128 * 64];    // 16 KB
  __shared__ __align__(16) u16 sB[BN * 64];     // 16 or 8 KB
  const int t = threadIdx.x, lane = t & 63;
  const int wave = t >> 6;
  const int g = lane >> 4, cl = lane & 15;
  const int z = blockIdx.z;
  const u16* B = P.B[z];
  const int n0 = blockIdx.x * BN, m0 = blockIdx.y * 128;
  const int wr = wave >> 1, wc = wave & 1;

  // staging offsets for a [R][64] u16 tile: chunk c -> row c>>3, slot c&7,
  // source col pre-swizzled (rule #21), read-side applies same XOR involution
  int srow[4], scol[4], soff[4];
#pragma unroll
  for (int j = 0; j < 4; ++j) {
    int c = j * 256 + t;
    srow[j] = c >> 3;
    scol[j] = ((c & 7) ^ (srow[j] & 7)) * 8;
    soff[j] = c * 16;
  }

  f32x4 acc[4][NF] = {};

  for (int k0 = 0; k0 < K; k0 += 64) {
#pragma unroll
    for (int j = 0; j < 4; ++j)
      gload_lds16(A + (size_t)(m0 + srow[j]) * K + k0 + scol[j], (uintptr_t)sA + soff[j]);
#pragma unroll
    for (int j = 0; j < BCH; ++j)
      gload_lds16(B + (size_t)(n0 + srow[j]) * K + k0 + scol[j], (uintptr_t)sB + soff[j]);
    __syncthreads();   // drains vmcnt(0): staging landed

    s16x8 af[4][2];
#pragma unroll
    for (int m = 0; m < 4; ++m) {
      int row = wr * 64 + m * 16 + cl;
#pragma unroll
      for (int kk = 0; kk < 2; ++kk)
        af[m][kk] = *(const s16x8*)&sA[row * 64 + (((kk * 4 + g) ^ (row & 7)) * 8)];
    }
#pragma unroll
    for (int n = 0; n < NF; ++n) {
      int row = wc * (BN / 2) + n * 16 + cl;
      s16x8 b0 = *(const s16x8*)&sB[row * 64 + ((g ^ (row & 7)) * 8)];
      s16x8 b1 = *(const s16x8*)&sB[row * 64 + (((4 + g) ^ (row & 7)) * 8)];
#pragma unroll
      for (int m = 0; m < 4; ++m) {
        acc[m][n] = MF<F16>(af[m][0], b0, acc[m][n]);
        acc[m][n] = MF<F16>(af[m][1], b1, acc[m][n]);
      }
    }
    __syncthreads();
  }

  // epilogue: C/D layout col=lane&15, row=(lane>>4)*4+reg  [m89]
  if (out_f32) {
#pragma unroll
    for (int m = 0; m < 4; ++m)
#pragma unroll
      for (int n = 0; n < NF; ++n)
#pragma unroll
        for (int r = 0; r < 4; ++r) {
          int row = m0 + wr * 64 + m * 16 + g * 4 + r;
          int col = n0 + wc * (BN / 2) + n * 16 + cl;
          CF[(size_t)row * N + col] = acc[m][n][r];
        }
  } else if (P.mode[z] == 1) {
    u16* VT = P.C0[z];
#pragma unroll
    for (int m = 0; m < 4; ++m)
#pragma unroll
      for (int n = 0; n < NF; ++n) {
        int row0 = m0 + wr * 64 + m * 16 + g * 4;
        int col = n0 + wc * (BN / 2) + n * 16 + cl;
        union { u16 u[4]; uint2 v; } pk;
#pragma unroll
        for (int r = 0; r < 4; ++r) pk.u[r] = f2bf(acc[m][n][r]);
        *(uint2*)&VT[(size_t)col * M + row0] = pk.v;
      }
  } else {
    u16* C = P.C0[z];
#pragma unroll
    for (int m = 0; m < 4; ++m)
#pragma unroll
      for (int n = 0; n < NF; ++n)
#pragma unroll
        for (int r = 0; r < 4; ++r) {
          int row = m0 + wr * 64 + m * 16 + g * 4 + r;
          int col = n0 + wc * (BN / 2) + n * 16 + cl;
          float v = acc[m][n][r];
          C[(size_t)row * N + col] = F16 ? f2h(v) : f2bf(v);
        }
  }
}

// ---------------- flash attention: fp16 QK^T, bf16 PV, no-max, 2-phase ----------------
// Q,K fp16 (1-term; 8x finer mantissa than bf16). P stays bf16 (exp(s) up to
// e^50 would overflow fp16); V bf16. LDS 50 KB. (R13-validated, absmax 0.017.)
__global__ __launch_bounds__(256, 2) void attn_kernel(
    const u16* __restrict__ Q, const u16* __restrict__ K,
    const u16* __restrict__ Vt,
    u16* __restrict__ Oh)
{
  __shared__ __align__(16) u16 sK [2][KVB * 64];   // fp16 [buf][key][d]  16KB
  __shared__ __align__(16) u16 sVt[2][DH * KVB];   // bf16 [buf][d][key]  16KB
  __shared__ __align__(16) u16 sP[128 * 72];       // bf16, 18KB, wave-private rows

  const int t = threadIdx.x, lane = t & 63, wave = t >> 6;
  const int g = lane >> 4, cl = lane & 15;
  const int h = blockIdx.x & (NH - 1), b = blockIdx.x >> 4;
  const int y = blockIdx.y;
  const int qi = (y < 4) ? (7 - y) : (y - 4);  // paired work balance + heavy-first
  const int q0 = qi * QBLK;
  const size_t rowbase = (size_t)b * SEQ;
  const int colbase = h * DH;
  const int MT = NB * SEQ;

  const u16* Kb  = K + rowbase * DMODEL + colbase;
  const u16* Vtb = Vt + (size_t)(h * DH) * MT + b * SEQ;

  int srow[2], scol[2], soff[2];
#pragma unroll
  for (int j = 0; j < 2; ++j) {
    int c = j * 256 + t;
    srow[j] = c >> 3;
    scol[j] = ((c & 7) ^ (srow[j] & 7)) * 8;
    soff[j] = c * 16;
  }

  // loop-invariant LDS read offsets
  int koff0[4], koff1[4];
#pragma unroll
  for (int n = 0; n < 4; ++n) {
    int row = n * 16 + cl;
    koff0[n] = row * 64 + ((g ^ (row & 7)) * 8);
    koff1[n] = row * 64 + (((4 + g) ^ (row & 7)) * 8);
  }
  int paoff[2][2];
#pragma unroll
  for (int kk = 0; kk < 2; ++kk) {
    paoff[kk][0] = (wave * 32 + cl) * 72 + kk * 32 + g * 8;
    paoff[kk][1] = (wave * 32 + 16 + cl) * 72 + kk * 32 + g * 8;
  }

  // Q fragments fp16 (A-op: lane holds A[row=cl][k=g*8+e], second mfma k+32)
  f16x8 qf[2][2];
#pragma unroll
  for (int mf = 0; mf < 2; ++mf) {
    int qrow = q0 + wave * 32 + mf * 16 + cl;
    const u16* pq = Q + (rowbase + qrow) * DMODEL + colbase + g * 8;
    qf[mf][0] = __builtin_bit_cast(f16x8, *(const s16x8*)pq);
    qf[mf][1] = __builtin_bit_cast(f16x8, *(const s16x8*)(pq + 32));
  }

  bf16x8 ones;
#pragma unroll
  for (int e = 0; e < 8; ++e) ones[e] = (__bf16)1.0f;

  f32x4 o_acc[2][4] = {};
  f32x4 o_l[2] = {};

  const int last = 2 * qi + 1;
  const int wrow0 = q0 + wave * 32;
  const int prow0 = wave * 32;

  // prologue: stage tile 0 into buffer 0
#pragma unroll
  for (int j = 0; j < 2; ++j) {
    gload_lds16(Kb + (size_t)srow[j] * DMODEL + scol[j],  (uintptr_t)&sK[0][0] + soff[j]);
    gload_lds16(Vtb + (size_t)srow[j] * MT + scol[j],     (uintptr_t)&sVt[0][0] + soff[j]);
  }
  __syncthreads();

  int cur = 0;
  for (int kt = 0; kt <= last; ++kt) {
    const int kv0 = kt * KVB;
    // issue next tile's staging FIRST (hidden under this tile's compute)
    if (kt < last) {
      const int nk = kv0 + KVB;
#pragma unroll
      for (int j = 0; j < 2; ++j) {
        gload_lds16(Kb + (size_t)(nk + srow[j]) * DMODEL + scol[j],
                    (uintptr_t)&sK[cur ^ 1][0] + soff[j]);
        gload_lds16(Vtb + (size_t)srow[j] * MT + nk + scol[j],
                    (uintptr_t)&sVt[cur ^ 1][0] + soff[j]);
      }
    }

    const bool skip = (wrow0 + 31) < kv0;   // wave fully masked (diag tiles)
    if (!skip) {
      const bool needmask = (kv0 + 63) > wrow0;

      // QK^T: fp16 single-term
      f32x4 s[2][4];
      __builtin_amdgcn_s_setprio(1);
#pragma unroll
      for (int n = 0; n < 4; ++n) {
        f16x8 k0 = __builtin_bit_cast(f16x8, *(const s16x8*)&sK[cur][koff0[n]]);
        f16x8 k1 = __builtin_bit_cast(f16x8, *(const s16x8*)&sK[cur][koff1[n]]);
#pragma unroll
        for (int mf = 0; mf < 2; ++mf) {
          f32x4 zz = {};
          zz = MFMA16H(qf[mf][0], k0, zz);
          zz = MFMA16H(qf[mf][1], k1, zz);
          s[mf][n] = zz;
        }
      }
      __builtin_amdgcn_s_setprio(0);

      // no-max softmax: p = exp2(s*log2e), zeroed past the diagonal
#pragma unroll
      for (int mf = 0; mf < 2; ++mf) {
#pragma unroll
        for (int r = 0; r < 4; ++r) {
          int qg = wrow0 + mf * 16 + g * 4 + r;
          int prow = prow0 + mf * 16 + g * 4 + r;
#pragma unroll
          for (int n = 0; n < 4; ++n) {
            float p = exp2f(s[mf][n][r] * LOG2E);
            if (needmask && (kv0 + n * 16 + cl > qg)) p = 0.0f;
            sP[prow * 72 + n * 16 + cl] = f2bf_rz(p);
          }
        }
      }

      // PV: O += P(32x64)*Vt ; l += P*1 (bf16 MFMA)
      __builtin_amdgcn_s_setprio(1);
#pragma unroll
      for (int kk = 0; kk < 2; ++kk) {
        bf16x8 pa0 = *(const bf16x8*)&sP[paoff[kk][0]];
        bf16x8 pa1 = *(const bf16x8*)&sP[paoff[kk][1]];
#pragma unroll
        for (int n = 0; n < 4; ++n) {
          bf16x8 vf = *(const bf16x8*)&sVt[cur][(kk == 0) ? koff0[n] : koff1[n]];
          o_acc[0][n] = MFMA16(pa0, vf, o_acc[0][n]);
          o_acc[1][n] = MFMA16(pa1, vf, o_acc[1][n]);
        }
        o_l[0] = MFMA16(pa0, ones, o_l[0]);
        o_l[1] = MFMA16(pa1, ones, o_l[1]);
      }
      __builtin_amdgcn_s_setprio(0);
    }

    __syncthreads();   // drains vmcnt(0): prefetch landed; frees buf cur
    cur ^= 1;
  }

  // epilogue: normalize by l, store bf16 (feeds bf16 Wo GEMM)
#pragma unroll
  for (int mf = 0; mf < 2; ++mf)
#pragma unroll
    for (int n = 0; n < 4; ++n)
#pragma unroll
      for (int r = 0; r < 4; ++r) {
        float ov = o_acc[mf][n][r] / o_l[mf][r];
        int qrow = q0 + wave * 32 + mf * 16 + g * 4 + r;
        size_t idx = (rowbase + qrow) * DMODEL + colbase + n * 16 + cl;
        Oh[idx] = f2bf(ov);
      }
}

extern "C" void kernel_launch(void* const* d_in, const int* in_sizes, int n_in,
                              void* d_out, int out_size, void* d_ws, size_t ws_size,
                              hipStream_t stream) {
  const float* x  = (const float*)d_in[0];
  const float* Wq = (const float*)d_in[1];
  const float* Wk = (const float*)d_in[2];
  const float* Wv = (const float*)d_in[3];
  const float* Wo = (const float*)d_in[4];
  float* out = (float*)d_out;

  const int M = NB * SEQ;      // 4096
  const int D = DMODEL;        // 1024
  char* ws = (char*)d_ws;
  const size_t MB = 1u << 20;
  u16* xh16 = (u16*)(ws + 0 * MB);    // 8 MB fp16
  u16* qh16 = (u16*)(ws + 8 * MB);    // 8 MB fp16
  u16* kh16 = (u16*)(ws + 16 * MB);   // 8 MB fp16
  u16* vt   = (u16*)(ws + 24 * MB);   // 8 MB bf16, transposed [1024][4096]
  u16* oh   = (u16*)(ws + 40 * MB);   // 8 MB bf16
  u16* wq16 = (u16*)(ws + 48 * MB);   // 2 MB each
  u16* wk16 = (u16*)(ws + 50 * MB);
  u16* wv16 = (u16*)(ws + 52 * MB);
  u16* wob  = (u16*)(ws + 54 * MB);

  // one fused cast launch: x,Wq,Wk,Wv -> fp16 ; Wo -> bf16
  {
    int total = M * D / 8 + 4 * (D * D / 8);
    cast_all_kernel<<<(total + 255) / 256, 256, 0, stream>>>(
        x, Wq, Wk, Wv, Wo, xh16, wq16, wk16, wv16, wob);
  }

  // fused QKV projections, fp16 1-term: Q,K fp16 out; V bf16 transposed out
  {
    GemmPtrs P;
    P.B[0] = wq16; P.B[1] = wk16; P.B[2] = wv16;
    P.C0[0] = qh16; P.C0[1] = kh16; P.C0[2] = vt;
    P.mode[0] = 0; P.mode[1] = 0; P.mode[2] = 1;
    gemm_bt_kernel<true, 128><<<dim3(D / 128, M / 128, 3), 256, 0, stream>>>(
        xh16, P, nullptr, M, D, D, 0);
  }

  // RoPE on fp16 Q,K (in place)
  rope_kernel<<<(2 * M * (D / 2) + 255) / 256, 256, 0, stream>>>(qh16, kh16);

  // causal flash attention: 512 blocks of 4 waves, pair-balanced heavy-first
  attn_kernel<<<dim3(NH * NB, 8), 256, 0, stream>>>(qh16, kh16, vt, oh);

  // output projection: bf16, 128x64 tile, 512 blocks (2/CU), direct f32 out
  {
    GemmPtrs P;
    P.B[0] = wob; P.B[1] = wob; P.B[2] = wob;
    P.C0[0] = nullptr; P.C0[1] = nullptr; P.C0[2] = nullptr;
    P.mode[0] = 0; P.mode[1] = 0; P.mode[2] = 0;
    gemm_bt_kernel<false, 64><<<dim3(D / 64, M / 128, 1), 256, 0, stream>>>(
        oh, P, out, M, D, D, 1);
  }
}